// Round 17
// baseline (66.394 us; speedup 1.0000x reference)
//
#include <hip/hip_runtime.h>

#define BDIM 128
#define TDIM 512
#define DDIM 64
#define HDIM 256
#define BH    (BDIM * HDIM)           // 32768
#define W_OFF (4 * BH)                // per-b {W0,W1}: 256 floats
#define HH_OFF (W_OFF + 256)          // hh: B x 1024

typedef short s16x8 __attribute__((ext_vector_type(8)));
typedef float f32x4 __attribute__((ext_vector_type(4)));

#if __has_builtin(__builtin_amdgcn_exp2f)
#define EXP2(x) __builtin_amdgcn_exp2f(x)
#else
#define EXP2(x) exp2f(x)
#endif
#define L2E 1.44269504f

__device__ __forceinline__ float rcpf(float x) { return __builtin_amdgcn_rcpf(x); }

__device__ __forceinline__ short f2bf(float f) {
  __bf16 b = (__bf16)f;
  return __builtin_bit_cast(short, b);
}

__device__ __forceinline__ s16x8 pack_bf8(float4 lo, float4 hi) {
  s16x8 v;
  v[0] = f2bf(lo.x); v[1] = f2bf(lo.y); v[2] = f2bf(lo.z); v[3] = f2bf(lo.w);
  v[4] = f2bf(hi.x); v[5] = f2bf(hi.y); v[6] = f2bf(hi.z); v[7] = f2bf(hi.w);
  return v;
}

__device__ __forceinline__ s16x8 pack_bf8s(float4 lo, float4 hi, float s) {
  s16x8 v;
  v[0] = f2bf(lo.x*s); v[1] = f2bf(lo.y*s); v[2] = f2bf(lo.z*s); v[3] = f2bf(lo.w*s);
  v[4] = f2bf(hi.x*s); v[5] = f2bf(hi.y*s); v[6] = f2bf(hi.z*s); v[7] = f2bf(hi.w*s);
  return v;
}

// hh = h0 @ Whh^T + biases via MFMA + W0/W1 sums (nt==16 branch). [R16]
__global__ __launch_bounds__(256) void hh_mfma_kernel(
    const float* __restrict__ h0, const float* __restrict__ Whh,
    const float* __restrict__ bih, const float* __restrict__ bhh,
    const float* __restrict__ x, const int* __restrict__ longp,
    float* __restrict__ sbuf)
{
  const int bt   = blockIdx.x;          // 0..7  (16 b's)
  const int nt   = blockIdx.y;          // 0..16
  const int tid  = threadIdx.x;
  const int wave = tid >> 6;            // 0..3
  const int lane = tid & 63;
  const int col  = lane & 15;
  const int kg   = lane >> 4;           // 0..3
  const int b0   = bt * 16;

  if (nt == 16) {                       // ---- W0/W1 full-t sums, 16 b's ----
    const int bl = tid >> 4, part = tid & 15;
    const int b = b0 + bl;
    const float* xb = x + (size_t)b * (TDIM * DDIM);
    const float inv_long = 1.0f / (float)(*longp);
    float sa = 0.f, sb = 0.f;
    for (int t = part; t < TDIM; t += 16) {
      float2 v = *(const float2*)(xb + (size_t)t * DDIM);
      sa += v.x; sb += v.y;
    }
    #pragma unroll
    for (int off = 1; off < 16; off <<= 1) {
      sa += __shfl_xor(sa, off, 64);
      sb += __shfl_xor(sb, off, 64);
    }
    if (part == 0) {
      sbuf[W_OFF + b * 2 + 0] = sa * inv_long;
      sbuf[W_OFF + b * 2 + 1] = sb;
    }
    return;
  }

  const int colw = nt * 64 + wave * 16 + col;
  const float bias = bih[colw] + bhh[colw];

  const float* arow = h0  + (size_t)(b0 + col) * HDIM + kg * 8;
  const float* brow = Whh + (size_t)colw * HDIM + kg * 8;

  f32x4 acc = {0.f, 0.f, 0.f, 0.f};
  #pragma unroll
  for (int s = 0; s < 8; ++s) {
    float4 a0 = *(const float4*)(arow + s * 32);
    float4 a1 = *(const float4*)(arow + s * 32 + 4);
    float4 q0 = *(const float4*)(brow + s * 32);
    float4 q1 = *(const float4*)(brow + s * 32 + 4);
    acc = __builtin_amdgcn_mfma_f32_16x16x32_bf16(
        pack_bf8(a0, a1), pack_bf8(q0, q1), acc, 0, 0, 0);
  }

  float* hh = sbuf + HH_OFF;
  #pragma unroll
  for (int r = 0; r < 4; ++r) {
    const int m = kg * 4 + r;           // b-local row
    hh[(size_t)(b0 + m) * 1024 + colw] = acc[r] + bias;
  }
}

// Grid: (128, 8), 512 threads = 8 waves. R12/R16 structure; ONLY change:
// merged-reciprocal gate math — ig*gg = (B-1)*rcp((1+A)(B+1)),
// og*tanh(cc) = (E-1)*rcp((1+D)(E+1)) — 8 trans-pipe ops per r instead of 10
// and one fewer serial rcp in the dependent chain.
__global__ __launch_bounds__(512, 4) void fused_lstm(
    const float* __restrict__ x, const float* __restrict__ c0,
    const float* __restrict__ Wih, const int* __restrict__ longp,
    float* __restrict__ sbuf)
{
  const int b    = blockIdx.x;
  const int hcq  = blockIdx.y;          // 0..7
  const int tid  = threadIdx.x;
  const int wave = tid >> 6;            // 0..7
  const int lane = tid & 63;
  const int col  = lane & 15;
  const int kg   = lane >> 4;           // 0..3
  const int hp   = wave & 1;
  const int tq   = wave >> 1;           // 0..3
  const int h    = hcq * 32 + hp * 16 + col;

  __shared__ float red[8 * 64];

  const float* hh = sbuf + HH_OFF;
  const float* xb = x + (size_t)b * (TDIM * DDIM);
  const float inv_long = 1.0f / (float)(*longp);

  const float SC[4] = {L2E, L2E, 2.f * L2E, L2E};
  float hhv[4];
  #pragma unroll
  for (int g = 0; g < 4; ++g)
    hhv[g] = hh[(size_t)b * 1024 + g * HDIM + h] * SC[g];
  const float cprev = c0[b * HDIM + h];

  // W_ih fragments (B operand), pre-scaled by SC[g]
  s16x8 wf[4][2];
  #pragma unroll
  for (int g = 0; g < 4; ++g) {
    const float4* wrow = (const float4*)(Wih + (size_t)(g * HDIM + h) * DDIM);
    #pragma unroll
    for (int ks = 0; ks < 2; ++ks)
      wf[g][ks] = pack_bf8s(wrow[kg * 2 + ks * 8], wrow[kg * 2 + ks * 8 + 1], SC[g]);
  }

  // A fragments: row = t0w + tb + col, k = kg*8 + j (+32); 1-deep prefetch
  const int t0w = tq * 128;
  const float* arow = xb + (size_t)(t0w + col) * DDIM + kg * 8;

  float4 nxt0 = *(const float4*)(arow + 0);
  float4 nxt1 = *(const float4*)(arow + 4);
  float4 nxt2 = *(const float4*)(arow + 32);
  float4 nxt3 = *(const float4*)(arow + 36);
  s16x8 a0 = pack_bf8(nxt0, nxt1);
  s16x8 a1 = pack_bf8(nxt2, nxt3);
  // lanes 0..15 hold x[t0w+tb+lane][0..3] in q0 -> raw (w0*long, w1) pair
  float w0c = nxt0.x, w1c = nxt0.y;
  if (tq == 0 && lane == 0) { w0c = 0.f; w1c = 0.f; }   // t=0 mask (tile 0)

  float s0h = 0.f, s1h = 0.f, s0c = 0.f, s1c = 0.f;

  for (int tb = 0; tb < 128; tb += 16) {
    const bool has_next = (tb + 16) < 128;
    if (has_next) {
      const float* p = arow + (size_t)(tb + 16) * DDIM;
      nxt0 = *(const float4*)(p + 0);
      nxt1 = *(const float4*)(p + 4);
      nxt2 = *(const float4*)(p + 32);
      nxt3 = *(const float4*)(p + 36);
    }

    f32x4 acc[4];
    #pragma unroll
    for (int g = 0; g < 4; ++g) {
      f32x4 zc = {hhv[g], hhv[g], hhv[g], hhv[g]};  // bias+hh folded into C
      zc = __builtin_amdgcn_mfma_f32_16x16x32_bf16(a0, wf[g][0], zc, 0, 0, 0);
      zc = __builtin_amdgcn_mfma_f32_16x16x32_bf16(a1, wf[g][1], zc, 0, 0, 0);
      acc[g] = zc;
    }

    #pragma unroll
    for (int r = 0; r < 4; ++r) {
      float wx = __shfl(w0c, kg * 4 + r, 64);
      float wy = __shfl(w1c, kg * 4 + r, 64);
      // merged-reciprocal gates (5 exp + 3 rcp, was 5+5):
      float eA = EXP2(-acc[0][r]);                  // i-gate
      float eC = EXP2(-acc[1][r]);                  // f-gate
      float eB = EXP2( acc[2][r]);                  // g-gate (2*L2E pre-scaled)
      float eD = EXP2(-acc[3][r]);                  // o-gate
      float igg = (eB - 1.f) * rcpf((1.f + eA) * (eB + 1.f));  // sig(i)*tanh(g)
      float fg  = rcpf(1.f + eC);
      float cc  = fmaf(fg, cprev, igg);
      float eE  = EXP2(cc * (2.f * L2E));
      float hv  = (eE - 1.f) * rcpf((1.f + eD) * (eE + 1.f)); // sig(o)*tanh(c)
      s0h = fmaf(hv, wx, s0h); s1h = fmaf(hv, wy, s1h);
      s0c = fmaf(cc, wx, s0c); s1c = fmaf(cc, wy, s1c);
    }

    if (has_next) {
      a0 = pack_bf8(nxt0, nxt1);
      a1 = pack_bf8(nxt2, nxt3);
      w0c = nxt0.x; w1c = nxt0.y;       // rows >= 16: no t=0 mask needed
    }
  }

  // reduce over the 4 k-groups (lanes sharing col)
  s0h += __shfl_xor(s0h, 16, 64); s0h += __shfl_xor(s0h, 32, 64);
  s1h += __shfl_xor(s1h, 16, 64); s1h += __shfl_xor(s1h, 32, 64);
  s0c += __shfl_xor(s0c, 16, 64); s0c += __shfl_xor(s0c, 32, 64);
  s1c += __shfl_xor(s1c, 16, 64); s1c += __shfl_xor(s1c, 32, 64);

  if (kg == 0) {
    red[wave * 64 +  0 + col] = s0h * inv_long;   // /long folded here
    red[wave * 64 + 16 + col] = s1h;
    red[wave * 64 + 32 + col] = s0c * inv_long;
    red[wave * 64 + 48 + col] = s1c;
  }
  __syncthreads();

  // combine the 4 t-quarters per h-slice (waves {hp, 2+hp, 4+hp, 6+hp})
  if (tid < 128) {
    const int hp2 = tid >> 6;
    const int q   = (tid >> 4) & 3;
    const int cc2 = tid & 15;
    const int o   = q * 16 + cc2;
    float s = red[(0 + hp2) * 64 + o] + red[(2 + hp2) * 64 + o] +
              red[(4 + hp2) * 64 + o] + red[(6 + hp2) * 64 + o];
    const int h2 = hcq * 32 + hp2 * 16 + cc2;
    sbuf[(size_t)q * BH + b * HDIM + h2] = s;
  }
}

// Epilogue as 4 MFMA GEMMs (R16-verified). Grid (8,8) x 256 thr.
__global__ __launch_bounds__(256) void out_mfma_kernel(
    const float* __restrict__ f1w, const float* __restrict__ f1b,
    const float* __restrict__ f2w, const float* __restrict__ f2b,
    const float* __restrict__ sbuf, float* __restrict__ out)
{
  const int bt   = blockIdx.x;          // 0..7
  const int kt   = blockIdx.y;          // 0..7
  const int tid  = threadIdx.x;
  const int wave = tid >> 6;            // 0..3
  const int lane = tid & 63;
  const int col  = lane & 15;
  const int kg   = lane >> 4;
  const int b0   = bt * 16;
  const int k0   = kt * 16;

  const int q        = (wave == 0) ? 0 : (wave == 1) ? 2 : (wave == 2) ? 1 : 3;
  const float* Wm    = (wave < 2) ? f1w : f2w;
  const float* bv    = (wave < 2) ? f1b : f2b;
  const int   kout   = (wave < 2) ? k0 : (128 + k0);
  const int   opl    = (wave & 1);      // 0: h-agg output, 1: c-agg output
  const int   wsel   = (wave < 2) ? 0 : 1;

  const float* arow = sbuf + (size_t)q * BH + (size_t)(b0 + col) * HDIM + kg * 8;
  const float* brow = Wm + (size_t)(k0 + col) * HDIM + kg * 8;

  f32x4 acc = {0.f, 0.f, 0.f, 0.f};
  #pragma unroll
  for (int s = 0; s < 8; ++s) {
    float4 a0 = *(const float4*)(arow + s * 32);
    float4 a1 = *(const float4*)(arow + s * 32 + 4);
    float4 q0 = *(const float4*)(brow + s * 32);
    float4 q1 = *(const float4*)(brow + s * 32 + 4);
    acc = __builtin_amdgcn_mfma_f32_16x16x32_bf16(
        pack_bf8(a0, a1), pack_bf8(q0, q1), acc, 0, 0, 0);
  }

  const float bw = bv[k0 + col];        // per-lane n = col
  #pragma unroll
  for (int r = 0; r < 4; ++r) {
    const int b = b0 + kg * 4 + r;      // C row = m = b-local
    const float Wv = sbuf[W_OFF + b * 2 + wsel];
    out[(size_t)opl * BH + (size_t)b * HDIM + kout + col] = acc[r] + bw * Wv;
  }
}

extern "C" void kernel_launch(void* const* d_in, const int* in_sizes, int n_in,
                              void* d_out, int out_size, void* d_ws, size_t ws_size,
                              hipStream_t stream) {
  const float* x   = (const float*)d_in[0];
  const float* h0  = (const float*)d_in[1];
  const float* c0  = (const float*)d_in[2];
  const float* Wih = (const float*)d_in[3];
  const float* Whh = (const float*)d_in[4];
  const float* bih = (const float*)d_in[5];
  const float* bhh = (const float*)d_in[6];
  const float* f1w = (const float*)d_in[7];
  const float* f1b = (const float*)d_in[8];
  const float* f2w = (const float*)d_in[9];
  const float* f2b = (const float*)d_in[10];
  const int*  longp = (const int*)d_in[11];
  float* out  = (float*)d_out;
  float* sbuf = (float*)d_ws;   // planes 512KB + W 1KB + hh 512KB

  dim3 gh(8, 17);
  hh_mfma_kernel<<<gh, 256, 0, stream>>>(h0, Whh, bih, bhh, x, longp, sbuf);
  dim3 g1(BDIM, 8);
  fused_lstm<<<g1, 512, 0, stream>>>(x, c0, Wih, longp, sbuf);
  dim3 go(8, 8);
  out_mfma_kernel<<<go, 256, 0, stream>>>(f1w, f1b, f2w, f2b, sbuf, out);
}

// Round 18
// 59.144 us; speedup vs baseline: 1.1226x; 1.1226x over previous
//
#include <hip/hip_runtime.h>

#define BDIM 128
#define TDIM 512
#define DDIM 64
#define HDIM 256
#define BH    (BDIM * HDIM)           // 32768
#define W_OFF (4 * BH)                // per-b {W0,W1}: 256 floats
#define HH_OFF (W_OFF + 256)          // hh: B x 1024

typedef short s16x8 __attribute__((ext_vector_type(8)));
typedef float f32x4 __attribute__((ext_vector_type(4)));

#if __has_builtin(__builtin_amdgcn_exp2f)
#define EXP2(x) __builtin_amdgcn_exp2f(x)
#else
#define EXP2(x) exp2f(x)
#endif
#define L2E 1.44269504f

__device__ __forceinline__ float rcpf(float x) { return __builtin_amdgcn_rcpf(x); }

__device__ __forceinline__ short f2bf(float f) {
  __bf16 b = (__bf16)f;
  return __builtin_bit_cast(short, b);
}

__device__ __forceinline__ s16x8 pack_bf8(float4 lo, float4 hi) {
  s16x8 v;
  v[0] = f2bf(lo.x); v[1] = f2bf(lo.y); v[2] = f2bf(lo.z); v[3] = f2bf(lo.w);
  v[4] = f2bf(hi.x); v[5] = f2bf(hi.y); v[6] = f2bf(hi.z); v[7] = f2bf(hi.w);
  return v;
}

__device__ __forceinline__ s16x8 pack_bf8s(float4 lo, float4 hi, float s) {
  s16x8 v;
  v[0] = f2bf(lo.x*s); v[1] = f2bf(lo.y*s); v[2] = f2bf(lo.z*s); v[3] = f2bf(lo.w*s);
  v[4] = f2bf(hi.x*s); v[5] = f2bf(hi.y*s); v[6] = f2bf(hi.z*s); v[7] = f2bf(hi.w*s);
  return v;
}

// hh = h0 @ Whh^T + biases via MFMA + W0/W1 sums (nt==16 branch). [R16/R17]
__global__ __launch_bounds__(256) void hh_mfma_kernel(
    const float* __restrict__ h0, const float* __restrict__ Whh,
    const float* __restrict__ bih, const float* __restrict__ bhh,
    const float* __restrict__ x, const int* __restrict__ longp,
    float* __restrict__ sbuf)
{
  const int bt   = blockIdx.x;          // 0..7  (16 b's)
  const int nt   = blockIdx.y;          // 0..16
  const int tid  = threadIdx.x;
  const int wave = tid >> 6;            // 0..3
  const int lane = tid & 63;
  const int col  = lane & 15;
  const int kg   = lane >> 4;           // 0..3
  const int b0   = bt * 16;

  if (nt == 16) {                       // ---- W0/W1 full-t sums, 16 b's ----
    const int bl = tid >> 4, part = tid & 15;
    const int b = b0 + bl;
    const float* xb = x + (size_t)b * (TDIM * DDIM);
    const float inv_long = 1.0f / (float)(*longp);
    float sa = 0.f, sb = 0.f;
    for (int t = part; t < TDIM; t += 16) {
      float2 v = *(const float2*)(xb + (size_t)t * DDIM);
      sa += v.x; sb += v.y;
    }
    #pragma unroll
    for (int off = 1; off < 16; off <<= 1) {
      sa += __shfl_xor(sa, off, 64);
      sb += __shfl_xor(sb, off, 64);
    }
    if (part == 0) {
      sbuf[W_OFF + b * 2 + 0] = sa * inv_long;
      sbuf[W_OFF + b * 2 + 1] = sb;
    }
    return;
  }

  const int colw = nt * 64 + wave * 16 + col;
  const float bias = bih[colw] + bhh[colw];

  const float* arow = h0  + (size_t)(b0 + col) * HDIM + kg * 8;
  const float* brow = Whh + (size_t)colw * HDIM + kg * 8;

  f32x4 acc = {0.f, 0.f, 0.f, 0.f};
  #pragma unroll
  for (int s = 0; s < 8; ++s) {
    float4 a0 = *(const float4*)(arow + s * 32);
    float4 a1 = *(const float4*)(arow + s * 32 + 4);
    float4 q0 = *(const float4*)(brow + s * 32);
    float4 q1 = *(const float4*)(brow + s * 32 + 4);
    acc = __builtin_amdgcn_mfma_f32_16x16x32_bf16(
        pack_bf8(a0, a1), pack_bf8(q0, q1), acc, 0, 0, 0);
  }

  float* hh = sbuf + HH_OFF;
  #pragma unroll
  for (int r = 0; r < 4; ++r) {
    const int m = kg * 4 + r;           // b-local row
    hh[(size_t)(b0 + m) * 1024 + colw] = acc[r] + bias;
  }
}

// Grid: (128, 4), 512 threads = 8 waves — SINGLE-GENERATION config: 512
// blocks = exactly 2 blocks/CU fully resident (was 1024 blocks ~2.7
// sequential generations, each paying the latency-bound prologue + a drain
// tail). Wave = (hp = wave&3: 16-h slice, tq = wave>>2: 256-t half) — 16
// K-steps per wave (was 8), halving prologue:work ratio. Body otherwise
// identical to the 51.7us R12/R16 loop (merged-reciprocal gates).
__global__ __launch_bounds__(512, 4) void fused_lstm(
    const float* __restrict__ x, const float* __restrict__ c0,
    const float* __restrict__ Wih, const int* __restrict__ longp,
    float* __restrict__ sbuf)
{
  const int b    = blockIdx.x;
  const int hcq  = blockIdx.y;          // 0..3 (64 h-cols per block)
  const int tid  = threadIdx.x;
  const int wave = tid >> 6;            // 0..7
  const int lane = tid & 63;
  const int col  = lane & 15;
  const int kg   = lane >> 4;           // 0..3
  const int hp   = wave & 3;            // h-slice
  const int tq   = wave >> 2;           // t-half (0..1)
  const int h    = hcq * 64 + hp * 16 + col;

  __shared__ float red[8 * 64];

  const float* hh = sbuf + HH_OFF;
  const float* xb = x + (size_t)b * (TDIM * DDIM);
  const float inv_long = 1.0f / (float)(*longp);

  const float SC[4] = {L2E, L2E, 2.f * L2E, L2E};
  float hhv[4];
  #pragma unroll
  for (int g = 0; g < 4; ++g)
    hhv[g] = hh[(size_t)b * 1024 + g * HDIM + h] * SC[g];
  const float cprev = c0[b * HDIM + h];

  // W_ih fragments (B operand), pre-scaled by SC[g]
  s16x8 wf[4][2];
  #pragma unroll
  for (int g = 0; g < 4; ++g) {
    const float4* wrow = (const float4*)(Wih + (size_t)(g * HDIM + h) * DDIM);
    #pragma unroll
    for (int ks = 0; ks < 2; ++ks)
      wf[g][ks] = pack_bf8s(wrow[kg * 2 + ks * 8], wrow[kg * 2 + ks * 8 + 1], SC[g]);
  }

  // A fragments: row = t0w + tb + col, k = kg*8 + j (+32); 1-deep prefetch
  const int t0w = tq * 256;
  const float* arow = xb + (size_t)(t0w + col) * DDIM + kg * 8;

  float4 nxt0 = *(const float4*)(arow + 0);
  float4 nxt1 = *(const float4*)(arow + 4);
  float4 nxt2 = *(const float4*)(arow + 32);
  float4 nxt3 = *(const float4*)(arow + 36);
  s16x8 a0 = pack_bf8(nxt0, nxt1);
  s16x8 a1 = pack_bf8(nxt2, nxt3);
  // lanes 0..15 hold x[t0w+tb+lane][0..3] in q0 -> raw (w0*long, w1) pair
  float w0c = nxt0.x, w1c = nxt0.y;
  if (tq == 0 && lane == 0) { w0c = 0.f; w1c = 0.f; }   // t=0 mask (tile 0)

  float s0h = 0.f, s1h = 0.f, s0c = 0.f, s1c = 0.f;

  for (int tb = 0; tb < 256; tb += 16) {   // 16 K-steps per wave
    const bool has_next = (tb + 16) < 256;
    if (has_next) {
      const float* p = arow + (size_t)(tb + 16) * DDIM;
      nxt0 = *(const float4*)(p + 0);
      nxt1 = *(const float4*)(p + 4);
      nxt2 = *(const float4*)(p + 32);
      nxt3 = *(const float4*)(p + 36);
    }

    f32x4 acc[4];
    #pragma unroll
    for (int g = 0; g < 4; ++g) {
      f32x4 zc = {hhv[g], hhv[g], hhv[g], hhv[g]};  // bias+hh folded into C
      zc = __builtin_amdgcn_mfma_f32_16x16x32_bf16(a0, wf[g][0], zc, 0, 0, 0);
      zc = __builtin_amdgcn_mfma_f32_16x16x32_bf16(a1, wf[g][1], zc, 0, 0, 0);
      acc[g] = zc;
    }

    #pragma unroll
    for (int r = 0; r < 4; ++r) {
      float wx = __shfl(w0c, kg * 4 + r, 64);
      float wy = __shfl(w1c, kg * 4 + r, 64);
      // merged-reciprocal gates (5 exp + 3 rcp):
      float eA = EXP2(-acc[0][r]);                  // i-gate
      float eC = EXP2(-acc[1][r]);                  // f-gate
      float eB = EXP2( acc[2][r]);                  // g-gate (2*L2E pre-scaled)
      float eD = EXP2(-acc[3][r]);                  // o-gate
      float igg = (eB - 1.f) * rcpf((1.f + eA) * (eB + 1.f));  // sig(i)*tanh(g)
      float fg  = rcpf(1.f + eC);
      float cc  = fmaf(fg, cprev, igg);
      float eE  = EXP2(cc * (2.f * L2E));
      float hv  = (eE - 1.f) * rcpf((1.f + eD) * (eE + 1.f)); // sig(o)*tanh(c)
      s0h = fmaf(hv, wx, s0h); s1h = fmaf(hv, wy, s1h);
      s0c = fmaf(cc, wx, s0c); s1c = fmaf(cc, wy, s1c);
    }

    if (has_next) {
      a0 = pack_bf8(nxt0, nxt1);
      a1 = pack_bf8(nxt2, nxt3);
      w0c = nxt0.x; w1c = nxt0.y;       // rows >= 16: no t=0 mask needed
    }
  }

  // reduce over the 4 k-groups (lanes sharing col)
  s0h += __shfl_xor(s0h, 16, 64); s0h += __shfl_xor(s0h, 32, 64);
  s1h += __shfl_xor(s1h, 16, 64); s1h += __shfl_xor(s1h, 32, 64);
  s0c += __shfl_xor(s0c, 16, 64); s0c += __shfl_xor(s0c, 32, 64);
  s1c += __shfl_xor(s1c, 16, 64); s1c += __shfl_xor(s1c, 32, 64);

  if (kg == 0) {
    red[wave * 64 +  0 + col] = s0h * inv_long;   // /long folded here
    red[wave * 64 + 16 + col] = s1h;
    red[wave * 64 + 32 + col] = s0c * inv_long;
    red[wave * 64 + 48 + col] = s1c;
  }
  __syncthreads();

  // combine the 2 t-halves per h-slice (waves {hp, 4+hp})
  if (tid < 256) {
    const int hp2 = tid >> 6;           // 0..3
    const int q   = (tid >> 4) & 3;
    const int cc2 = tid & 15;
    const int o   = q * 16 + cc2;
    float s = red[hp2 * 64 + o] + red[(4 + hp2) * 64 + o];
    const int h2 = hcq * 64 + hp2 * 16 + cc2;
    sbuf[(size_t)q * BH + b * HDIM + h2] = s;
  }
}

// Epilogue as 4 MFMA GEMMs (R16-verified). Grid (8,8) x 256 thr.
__global__ __launch_bounds__(256) void out_mfma_kernel(
    const float* __restrict__ f1w, const float* __restrict__ f1b,
    const float* __restrict__ f2w, const float* __restrict__ f2b,
    const float* __restrict__ sbuf, float* __restrict__ out)
{
  const int bt   = blockIdx.x;          // 0..7
  const int kt   = blockIdx.y;          // 0..7
  const int tid  = threadIdx.x;
  const int wave = tid >> 6;            // 0..3
  const int lane = tid & 63;
  const int col  = lane & 15;
  const int kg   = lane >> 4;
  const int b0   = bt * 16;
  const int k0   = kt * 16;

  const int q        = (wave == 0) ? 0 : (wave == 1) ? 2 : (wave == 2) ? 1 : 3;
  const float* Wm    = (wave < 2) ? f1w : f2w;
  const float* bv    = (wave < 2) ? f1b : f2b;
  const int   kout   = (wave < 2) ? k0 : (128 + k0);
  const int   opl    = (wave & 1);      // 0: h-agg output, 1: c-agg output
  const int   wsel   = (wave < 2) ? 0 : 1;

  const float* arow = sbuf + (size_t)q * BH + (size_t)(b0 + col) * HDIM + kg * 8;
  const float* brow = Wm + (size_t)(k0 + col) * HDIM + kg * 8;

  f32x4 acc = {0.f, 0.f, 0.f, 0.f};
  #pragma unroll
  for (int s = 0; s < 8; ++s) {
    float4 a0 = *(const float4*)(arow + s * 32);
    float4 a1 = *(const float4*)(arow + s * 32 + 4);
    float4 q0 = *(const float4*)(brow + s * 32);
    float4 q1 = *(const float4*)(brow + s * 32 + 4);
    acc = __builtin_amdgcn_mfma_f32_16x16x32_bf16(
        pack_bf8(a0, a1), pack_bf8(q0, q1), acc, 0, 0, 0);
  }

  const float bw = bv[k0 + col];        // per-lane n = col
  #pragma unroll
  for (int r = 0; r < 4; ++r) {
    const int b = b0 + kg * 4 + r;      // C row = m = b-local
    const float Wv = sbuf[W_OFF + b * 2 + wsel];
    out[(size_t)opl * BH + (size_t)b * HDIM + kout + col] = acc[r] + bw * Wv;
  }
}

extern "C" void kernel_launch(void* const* d_in, const int* in_sizes, int n_in,
                              void* d_out, int out_size, void* d_ws, size_t ws_size,
                              hipStream_t stream) {
  const float* x   = (const float*)d_in[0];
  const float* h0  = (const float*)d_in[1];
  const float* c0  = (const float*)d_in[2];
  const float* Wih = (const float*)d_in[3];
  const float* Whh = (const float*)d_in[4];
  const float* bih = (const float*)d_in[5];
  const float* bhh = (const float*)d_in[6];
  const float* f1w = (const float*)d_in[7];
  const float* f1b = (const float*)d_in[8];
  const float* f2w = (const float*)d_in[9];
  const float* f2b = (const float*)d_in[10];
  const int*  longp = (const int*)d_in[11];
  float* out  = (float*)d_out;
  float* sbuf = (float*)d_ws;   // planes 512KB + W 1KB + hh 512KB

  dim3 gh(8, 17);
  hh_mfma_kernel<<<gh, 256, 0, stream>>>(h0, Whh, bih, bhh, x, longp, sbuf);
  dim3 g1(BDIM, 4);
  fused_lstm<<<g1, 512, 0, stream>>>(x, c0, Wih, longp, sbuf);
  dim3 go(8, 8);
  out_mfma_kernel<<<go, 256, 0, stream>>>(f1w, f1b, f2w, f2b, sbuf, out);
}